// Round 1
// 282.415 us; speedup vs baseline: 1.0053x; 1.0053x over previous
//
#include <hip/hip_runtime.h>

typedef unsigned short u16;
typedef __attribute__((ext_vector_type(8))) short short8;
typedef __attribute__((ext_vector_type(4))) float f32x4;

#define LSTR 68     // padded leading dim for f32 LDS tiles (68%32=4 -> 2-way max)
#define ASTR 1032   // padded bf16 leading dim (1024+8): 16B-aligned rows, 2-way-max
#define FILLB 2048  // grid-stride fill blocks

__device__ __forceinline__ u16 f2bf(float f){
  union { float f; unsigned int i; } v; v.f = f;
  unsigned int x = v.i;
  return (u16)((x + 0x7FFFu + ((x >> 16) & 1u)) >> 16);   // RNE
}

// convert 8 contiguous f32 to a bf16 MFMA fragment
__device__ __forceinline__ short8 cvt8(const float* __restrict__ p){
  float4 a = *(const float4*)p;
  float4 b = *(const float4*)(p + 4);
  short8 r;
  r[0]=(short)f2bf(a.x); r[1]=(short)f2bf(a.y); r[2]=(short)f2bf(a.z); r[3]=(short)f2bf(a.w);
  r[4]=(short)f2bf(b.x); r[5]=(short)f2bf(b.y); r[6]=(short)f2bf(b.z); r[7]=(short)f2bf(b.w);
  return r;
}

// ---------------------------------------------------------------------------
// mm4: out[o] for o = i*16+cg (consecutive-lane rows -> 2-way LDS conflicts max)
// ---------------------------------------------------------------------------
__device__ __forceinline__ void mm4(const float* __restrict__ X, const float* __restrict__ W,
                                    const float* __restrict__ bias, int r, int cg, float out4[4])
{
  const float* xrow = X + r*LSTR;
  #pragma unroll
  for (int i=0;i<4;i++){
    int o = i*16 + cg;
    const float* wrow = W + o*LSTR;
    float acc = bias[o];
    #pragma unroll
    for (int d=0; d<64; d+=4){
      float4 w4 = *(const float4*)(wrow + d);
      float4 x4 = *(const float4*)(xrow + d);
      acc += x4.x*w4.x + x4.y*w4.y + x4.z*w4.z + x4.w*w4.w;
    }
    out4[i] = acc;
  }
}

__device__ __forceinline__ void ln4(float v[4], const float* __restrict__ lnw, int cg)
{
  float s = v[0]+v[1]+v[2]+v[3];
  float q = v[0]*v[0]+v[1]*v[1]+v[2]*v[2]+v[3]*v[3];
  #pragma unroll
  for (int m=1;m<16;m<<=1){ s += __shfl_xor(s,m); q += __shfl_xor(q,m); }
  float mn  = s * (1.f/64.f);
  float var = q * (1.f/64.f) - mn*mn;
  float rs  = rsqrtf(fmaxf(var,0.f) + 1e-5f);
  #pragma unroll
  for (int i=0;i<4;i++) v[i] = (v[i]-mn)*rs*lnw[i*16+cg];
}

__device__ __forceinline__ void attn_iter(const float* __restrict__ qsrc,
    const float* __restrict__ wq, const float* __restrict__ lqb, const float* __restrict__ lnc,
    float* __restrict__ qns, float* __restrict__ ps,
    const float* __restrict__ kks, const float* __restrict__ vis,
    int r, int cg, float a4[4])
{
  float qn4[4];
  mm4(qsrc, wq, lqb, r, cg, qn4);
  ln4(qn4, lnc, cg);
  #pragma unroll
  for (int i=0;i<4;i++) qns[r*LSTR + i*16 + cg] = qn4[i];
  __syncthreads();
  // scores: this thread computes S[r][cg]
  float acc = 0.f;
  #pragma unroll
  for (int d=0;d<64;d+=4){
    float4 a  = *(const float4*)(qns + r*LSTR + d);
    float4 bv = *(const float4*)(kks + cg*LSTR + d);
    acc += a.x*bv.x + a.y*bv.y + a.z*bv.z + a.w*bv.w;
  }
  acc *= 0.125f;                         // 1/sqrt(64)
  float mx = acc;
  #pragma unroll
  for (int m=1;m<16;m<<=1) mx = fmaxf(mx, __shfl_xor(mx,m));
  float e = __expf(acc - mx);
  float sm = e;
  #pragma unroll
  for (int m=1;m<16;m<<=1) sm += __shfl_xor(sm,m);
  ps[r*17+cg] = e / sm;
  __syncthreads();
  int c0 = cg*4;
  #pragma unroll
  for (int i=0;i<4;i++){
    int o = c0+i; float s = 0.f;
    #pragma unroll
    for (int c=0;c<16;c++) s += ps[r*17+c]*vis[c*LSTR+o];
    a4[i] = s;
  }
}

// ---------------------------------------------------------------------------
// k_main: blocks 0..127 = fused LN + qkv-proj + attention per (b,h).
//         blocks 128..128+FILLB-1 = grid-stride ob-broadcast fill of the
//         32640 inactive output rows (s>=16). The heavy-but-tiny attention
//         compute hides under the fill's HBM write bandwidth.
// ---------------------------------------------------------------------------
__global__ __launch_bounds__(256) void k_main(const float* __restrict__ x,
    const float* __restrict__ lna, const float* __restrict__ lnb,
    const float* __restrict__ qw, const float* __restrict__ qb,
    const float* __restrict__ kw, const float* __restrict__ vw,
    const float* __restrict__ vb,
    const float* __restrict__ lnc, const float* __restrict__ lnd,
    const float* __restrict__ lqw, const float* __restrict__ lqb,
    const float* __restrict__ lkw, const float* __restrict__ lkb,
    const float* __restrict__ lvw, const float* __restrict__ lvb,
    const float* __restrict__ ob, u16* __restrict__ attn, float* __restrict__ out)
{
  __shared__ u16 An[16*ASTR];                              // normalized x, bf16 (33 KB)
  __shared__ float wqs[64*LSTR], wks[64*LSTR], wvs[64*LSTR];  // 52 KB
  __shared__ float qs[16*LSTR], ks[16*LSTR], vs[16*LSTR];
  __shared__ float kks[16*LSTR], vis[16*LSTR], qns[16*LSTR], qcs[16*LSTR];
  __shared__ float ps[16*17];
  __shared__ float sb[5*64];   // lqb, lkb, lvb, lnc, lnd

  int tid = threadIdx.x;

  if (blockIdx.x >= 128){
    // ---- grid-stride fill of rows s>=16 with ob ----
    int fb = blockIdx.x - 128;
    const int SPAN = 4080*256;            // f4 per batch (rows 16..4095)
    const int TOT  = 8*SPAN;              // 8,355,840 float4s
    float4 val = *(const float4*)(ob + tid*4);   // col pattern fixed per thread
    for (int idx = fb*256 + tid; idx < TOT; idx += FILLB*256){
      int b   = idx / SPAN;
      int rem = idx - b*SPAN;
      *((float4*)out + ((size_t)b*1048576 + 4096 + rem)) = val;
    }
    return;
  }

  // ---- fused LN + projections + attention for (b,h) ----
  int b = blockIdx.x >> 4, h = blockIdx.x & 15;
  int wave = tid>>6, lane = tid&63;
  int r = tid >> 4, l16 = tid & 15;

  // stage 64x64 small weights + biases/ln-weights
  for (int i = tid; i < 1024; i += 256){
    int o = i >> 4, d = (i & 15)*4;
    *(float4*)(wqs + o*LSTR + d) = *(const float4*)(lqw + i*4);
    *(float4*)(wks + o*LSTR + d) = *(const float4*)(lkw + i*4);
    *(float4*)(wvs + o*LSTR + d) = *(const float4*)(lvw + i*4);
  }
  if (tid < 64){
    sb[tid]       = lqb[tid];
    sb[64  + tid] = lkb[tid];
    sb[128 + tid] = lvb[tid];
    sb[192 + tid] = lnc[tid];
    sb[256 + tid] = lnd[tid];
  }

  // LN of the 16 active rows of batch b; store NORMALIZED value only
  // (lna/lnb get folded into the projection-weight conversion)
  const float* xr = x + ((size_t)b*4096 + r)*1024;
  float4 vv[16];
  float sum = 0.f, sq = 0.f;
  #pragma unroll
  for (int j=0;j<16;j++){
    vv[j] = *(const float4*)(xr + (j*16 + l16)*4);
    sum += vv[j].x+vv[j].y+vv[j].z+vv[j].w;
    sq  += vv[j].x*vv[j].x + vv[j].y*vv[j].y + vv[j].z*vv[j].z + vv[j].w*vv[j].w;
  }
  #pragma unroll
  for (int m=1;m<16;m<<=1){ sum += __shfl_xor(sum,m); sq += __shfl_xor(sq,m); }
  float mn  = sum * (1.f/1024.f);
  float var = sq  * (1.f/1024.f) - mn*mn;          // biased variance, torch-style
  float rs  = rsqrtf(fmaxf(var, 0.f) + 1e-5f);
  #pragma unroll
  for (int j=0;j<16;j++){
    int c = (j*16 + l16)*4;
    ushort4 oa;
    oa.x = f2bf((vv[j].x-mn)*rs); oa.y = f2bf((vv[j].y-mn)*rs);
    oa.z = f2bf((vv[j].z-mn)*rs); oa.w = f2bf((vv[j].w-mn)*rs);
    *(ushort4*)(An + r*ASTR + c) = oa;
  }
  __syncthreads();

  // projections: 12 tiles of 16x16 (q,k,v x 4 col-tiles of this head), 3 per wave
  int m_lane = lane & 15, quad = lane >> 4;
  #pragma unroll
  for (int tt=0; tt<3; ++tt){
    int t = wave*3 + tt;
    int mat = t >> 2, ncl = t & 3;
    const float* W  = (mat==0) ? qw  : ((mat==1) ? kw  : vw);
    const float* sc = (mat==0) ? lna : lnb;      // fold LN weight into W
    int ncol = h*64 + ncl*16 + m_lane;
    const u16*   ap = An + m_lane*ASTR + quad*8;
    const float* bp = W + (size_t)ncol*1024 + quad*8;
    const float* sp = sc + quad*8;
    f32x4 acc = {0.f,0.f,0.f,0.f};
    #pragma unroll 4
    for (int k0=0;k0<1024;k0+=32){
      short8 af = *(const short8*)(ap + k0);
      float4 w0 = *(const float4*)(bp + k0);
      float4 w1 = *(const float4*)(bp + k0 + 4);
      float4 s0 = *(const float4*)(sp + k0);
      float4 s1 = *(const float4*)(sp + k0 + 4);
      short8 bf;
      bf[0]=(short)f2bf(w0.x*s0.x); bf[1]=(short)f2bf(w0.y*s0.y);
      bf[2]=(short)f2bf(w0.z*s0.z); bf[3]=(short)f2bf(w0.w*s0.w);
      bf[4]=(short)f2bf(w1.x*s1.x); bf[5]=(short)f2bf(w1.y*s1.y);
      bf[6]=(short)f2bf(w1.z*s1.z); bf[7]=(short)f2bf(w1.w*s1.w);
      acc = __builtin_amdgcn_mfma_f32_16x16x32_bf16(af, bf, acc, 0, 0, 0);
    }
    float bias = (mat==0) ? qb[ncol] : ((mat==2) ? vb[ncol] : 0.f);
    float* dst = (mat==0) ? qs : ((mat==1) ? ks : vs);
    #pragma unroll
    for (int i=0;i<4;i++)
      dst[(quad*4+i)*LSTR + ncl*16 + m_lane] = acc[i] + bias;   // C/D: col=lane&15, row=quad*4+i
  }
  __syncthreads();

  int cg = tid & 15, c0 = cg*4;
  // kn = LN_d(k @ lkw^T + lkb),  vi = v @ lvw^T + lvb   (iteration-invariant)
  float kk4[4]; mm4(ks, wks, sb+64, r, cg, kk4); ln4(kk4, sb+256, cg);
  float vi4[4]; mm4(vs, wvs, sb+128, r, cg, vi4);
  #pragma unroll
  for (int i=0;i<4;i++){ kks[r*LSTR + i*16 + cg] = kk4[i]; vis[r*LSTR + i*16 + cg] = vi4[i]; }
  __syncthreads();

  float a4[4];
  attn_iter(qs, wqs, sb+0, sb+192, qns, ps, kks, vis, r, cg, a4);   // iter 0
  #pragma unroll
  for (int i=0;i<4;i++) qcs[r*LSTR + c0 + i] = qs[r*LSTR + c0 + i] + a4[i];  // qcur = q + A0
  __syncthreads();
  attn_iter(qcs, wqs, sb+0, sb+192, qns, ps, kks, vis, r, cg, a4);  // iter 1 (break fires)

  ushort4 ov;
  ov.x=f2bf(a4[0]); ov.y=f2bf(a4[1]); ov.z=f2bf(a4[2]); ov.w=f2bf(a4[3]);
  *(ushort4*)(attn + (size_t)(b*16 + r)*1024 + h*64 + c0) = ov;
}

// ---------------------------------------------------------------------------
// Output projection of the 128 active rows: 512 tile-waves, 2 waves/block.
// ---------------------------------------------------------------------------
__global__ __launch_bounds__(128) void k_oproj(const u16* __restrict__ attn,
    const float* __restrict__ ow, const float* __restrict__ ob, float* __restrict__ out)
{
  int tid = threadIdx.x, wave = tid>>6, lane = tid&63;
  int tile = blockIdx.x*2 + wave;              // 0..511
  int mt = tile >> 6, nt = tile & 63;
  int m_lane = lane & 15, quad = lane >> 4;
  const u16*   ap = attn + (size_t)(mt*16 + m_lane)*1024 + quad*8;
  const float* bp = ow   + (size_t)(nt*16 + m_lane)*1024 + quad*8;
  f32x4 acc = {0.f,0.f,0.f,0.f};
  #pragma unroll 4
  for (int k0=0;k0<1024;k0+=32){
    short8 af = *(const short8*)(ap + k0);
    short8 bf = cvt8(bp + k0);
    acc = __builtin_amdgcn_mfma_f32_16x16x32_bf16(af, bf, acc, 0, 0, 0);
  }
  int n = nt*16 + m_lane;
  float bias = ob[n];
  #pragma unroll
  for (int i=0;i<4;i++){
    int s = quad*4 + i;                        // tile-local row = seq pos (mt = batch)
    out[((size_t)mt*4096 + s)*1024 + n] = acc[i] + bias;
  }
}

// ---------------------------------------------------------------------------
extern "C" void kernel_launch(void* const* d_in, const int* in_sizes, int n_in,
                              void* d_out, int out_size, void* d_ws, size_t ws_size,
                              hipStream_t stream)
{
  const float* x    = (const float*)d_in[0];
  const float* qw   = (const float*)d_in[1];
  const float* qb   = (const float*)d_in[2];
  const float* kw   = (const float*)d_in[3];
  const float* vw   = (const float*)d_in[4];
  const float* vb   = (const float*)d_in[5];
  const float* ow   = (const float*)d_in[6];
  const float* ob   = (const float*)d_in[7];
  const float* lna  = (const float*)d_in[8];
  const float* lnb  = (const float*)d_in[9];
  const float* lnc  = (const float*)d_in[10];
  const float* lnd  = (const float*)d_in[11];
  const float* lqw  = (const float*)d_in[12];
  const float* lqb  = (const float*)d_in[13];
  const float* lkw  = (const float*)d_in[14];
  const float* lkb  = (const float*)d_in[15];
  const float* lvw  = (const float*)d_in[16];
  const float* lvb  = (const float*)d_in[17];

  u16* attn = (u16*)d_ws;                  // 128*1024 bf16 = 256 KiB
  float* out = (float*)d_out;

  k_main <<<128 + FILLB, 256, 0, stream>>>(x, lna, lnb, qw, qb, kw, vw, vb,
                                           lnc, lnd, lqw, lqb, lkw, lkb, lvw, lvb,
                                           ob, attn, out);
  k_oproj<<<256, 128, 0, stream>>>(attn, ow, ob, out);
}